// Round 6
// baseline (222.788 us; speedup 1.0000x reference)
//
#include <hip/hip_runtime.h>
#include <hip/hip_cooperative_groups.h>
#include <stdint.h>
#include <stddef.h>

namespace cg = cooperative_groups;

typedef __bf16 bf16;
typedef __bf16 bf16x8 __attribute__((ext_vector_type(8)));
typedef float f32x4 __attribute__((ext_vector_type(4)));

// ---------------------------------------------------------------------------
// async global->LDS, 16B per lane. LDS dest is wave-uniform base + lane*16.
// ---------------------------------------------------------------------------
__device__ __forceinline__ void global_to_lds16(const void* g, void* l) {
  const __attribute__((address_space(1))) unsigned* gp =
      reinterpret_cast<const __attribute__((address_space(1))) unsigned*>(
          reinterpret_cast<uintptr_t>(g));
  __attribute__((address_space(3))) unsigned* lp =
      reinterpret_cast<__attribute__((address_space(3))) unsigned*>(
          reinterpret_cast<uintptr_t>(l));
  __builtin_amdgcn_global_load_lds(gp, lp, 16, 0, 0);
}

// ---------------------------------------------------------------------------
// 128x128-tile NT GEMM body, BK=64. C = A * B^T. K=1024, ld=1024.
// smem: 32 KB. K-accumulation order identical across rounds -> bit-identical.
// ---------------------------------------------------------------------------
template <typename OutT>
__device__ __forceinline__ void gemm128_body(char* smem,
                                             const bf16* __restrict__ A,
                                             const bf16* __restrict__ B,
                                             OutT* __restrict__ C,
                                             int bx, int by) {
  bf16* Asl[2] = {(bf16*)smem, (bf16*)(smem + 8192)};
  bf16* Bsl[2] = {(bf16*)(smem + 16384), (bf16*)(smem + 24576)};

  const int tid = threadIdx.x;
  const int wave = tid >> 6, lane = tid & 63;
  const int quad = lane >> 4, l16 = lane & 15;
  const int rowBase = by * 128;
  const int colBase = bx * 128;
  const int waveM = (wave >> 1) * 64, waveN = (wave & 1) * 64;

  const int sr = tid >> 2;
  const int sc = (tid & 3) * 8;
  const bf16* Ag0 = A + (size_t)(rowBase + sr) * 1024 + sc;
  const bf16* Ag1 = Ag0 + (size_t)64 * 1024;
  const bf16* Bg0 = B + (size_t)(colBase + sr) * 1024 + sc;
  const bf16* Bg1 = Bg0 + (size_t)64 * 1024;

  char* lA0  = (char*)Asl[0] + wave * 1024;
  char* lA0b = lA0 + 4096;
  char* lA1  = (char*)Asl[1] + wave * 1024;
  char* lA1b = lA1 + 4096;
  char* lB0  = (char*)Bsl[0] + wave * 1024;
  char* lB0b = lB0 + 4096;
  char* lB1  = (char*)Bsl[1] + wave * 1024;
  char* lB1b = lB1 + 4096;

  f32x4 acc[4][4] = {};

  for (int k0 = 0; k0 < 1024; k0 += 64) {
    global_to_lds16(Ag0 + k0,      lA0);
    global_to_lds16(Ag1 + k0,      lA0b);
    global_to_lds16(Ag0 + k0 + 32, lA1);
    global_to_lds16(Ag1 + k0 + 32, lA1b);
    global_to_lds16(Bg0 + k0,      lB0);
    global_to_lds16(Bg1 + k0,      lB0b);
    global_to_lds16(Bg0 + k0 + 32, lB1);
    global_to_lds16(Bg1 + k0 + 32, lB1b);
    __syncthreads();
#pragma unroll
    for (int kk = 0; kk < 2; kk++) {
      bf16x8 af[4], bfr[4];
#pragma unroll
      for (int mi = 0; mi < 4; mi++)
        af[mi] = *(const bf16x8*)(Asl[kk] + (waveM + mi * 16 + l16) * 32 + quad * 8);
#pragma unroll
      for (int ni = 0; ni < 4; ni++)
        bfr[ni] = *(const bf16x8*)(Bsl[kk] + (waveN + ni * 16 + l16) * 32 + quad * 8);
#pragma unroll
      for (int mi = 0; mi < 4; mi++)
#pragma unroll
        for (int ni = 0; ni < 4; ni++)
          acc[mi][ni] = __builtin_amdgcn_mfma_f32_16x16x32_bf16(af[mi], bfr[ni],
                                                                acc[mi][ni], 0, 0, 0);
    }
    __syncthreads();
  }

  OutT* Cb = C + (size_t)(rowBase + waveM) * 1024 + colBase + waveN;
#pragma unroll
  for (int mi = 0; mi < 4; mi++)
#pragma unroll
    for (int ni = 0; ni < 4; ni++)
#pragma unroll
      for (int r = 0; r < 4; r++)
        Cb[(size_t)(mi * 16 + quad * 4 + r) * 1024 + ni * 16 + l16] =
            (OutT)acc[mi][ni][r];
}

// ---------------------------------------------------------------------------
// Shared argument block for all phases.
// ---------------------------------------------------------------------------
struct AllArgs {
  const float* cvt_src[5]; bf16* cvt_dst[5];
  const float* tr_src[6];  bf16* tr_dst[6];
  const float* Wdec; const int* praw; bf16* Gbf;
  const float* x; bf16* xbf;
  const bf16* A1[6]; const bf16* B1[6]; bf16* C1[6];
  const bf16* A2[3]; const bf16* B2[3]; bf16* C2[3];
  const bf16* A3; const bf16* B3; bf16* C3;
  const bf16* A4; const bf16* B4; bf16* C4;
  const bf16* Af; const bf16* Bf; float* Cf;
};

// prep unit u in [0, 9216):
//   [0,2560) cvt W, [2560,4096) transpose W, [4096,5120) G build,
//   [5120,9216) x fp32->bf16 convert (2048 elems/unit)
__device__ __forceinline__ void prep_unit(const AllArgs& p, int u, char* smem) {
  const int tid = threadIdx.x;
  if (u < 2560) {
    const int m = u >> 9, blk = u & 511;
    const float* __restrict__ src = p.cvt_src[m];
    bf16* __restrict__ dst = p.cvt_dst[m];
    const int i = (blk * 256 + tid) * 8;
    float4 a = *(const float4*)(src + i);
    float4 c = *(const float4*)(src + i + 4);
    bf16x8 o;
    o[0] = (bf16)a.x; o[1] = (bf16)a.y; o[2] = (bf16)a.z; o[3] = (bf16)a.w;
    o[4] = (bf16)c.x; o[5] = (bf16)c.y; o[6] = (bf16)c.z; o[7] = (bf16)c.w;
    *(bf16x8*)(dst + i) = o;
  } else if (u < 4096) {
    const int t = u - 2560;
    const int m = t >> 8, r = t & 255;
    const float* __restrict__ src = p.tr_src[m];
    bf16* __restrict__ dst = p.tr_dst[m];
    bf16(*tile)[65] = reinterpret_cast<bf16(*)[65]>(smem);
    const int bx = (r & 15) * 64;
    const int by = (r >> 4) * 64;
    const int tx = tid & 63;
    const int ty4 = tid >> 6;
#pragma unroll
    for (int rr = 0; rr < 16; rr++) {
      int row = ty4 * 16 + rr;
      tile[row][tx] = (bf16)src[(size_t)(by + row) * 1024 + bx + tx];
    }
    __syncthreads();
#pragma unroll
    for (int rr = 0; rr < 16; rr++) {
      int row = ty4 * 16 + rr;
      dst[(size_t)(bx + row) * 1024 + by + tx] = tile[tx][row];
    }
  } else if (u < 5120) {
    const int j = u - 4096;
    float* row = (float*)smem;
    int* perm_l = (int*)(smem + 4096);
    int* nzp = (int*)(smem + 4096 + 1024);
#pragma unroll
    for (int c = 0; c < 4; c++) row[tid * 4 + c] = 0.f;
    if (tid == 0) *nzp = 0;
    __syncthreads();
    if (tid < 128 && p.praw[2 * tid + 1] != 0) atomicOr(nzp, 1);
    __syncthreads();
    const int is64 = (*nzp == 0);
    perm_l[tid] = is64 ? p.praw[2 * tid] : p.praw[tid];
    __syncthreads();
    atomicAdd(&row[perm_l[tid]], p.Wdec[(size_t)j * 256 + tid]);
    __syncthreads();
#pragma unroll
    for (int c = 0; c < 4; c++)
      p.Gbf[(size_t)j * 1024 + tid * 4 + c] = (bf16)row[tid * 4 + c];
  } else {
    const int i = (u - 5120) * 2048 + tid * 8;
    float4 v0 = *(const float4*)(p.x + i);
    float4 v1 = *(const float4*)(p.x + i + 4);
    bf16x8 o;
    o[0] = (bf16)v0.x; o[1] = (bf16)v0.y; o[2] = (bf16)v0.z; o[3] = (bf16)v0.w;
    o[4] = (bf16)v1.x; o[5] = (bf16)v1.y; o[6] = (bf16)v1.z; o[7] = (bf16)v1.w;
    *(bf16x8*)(p.xbf + i) = o;
  }
}

// ---------------------------------------------------------------------------
// Cooperative mega kernel; every phase grid-strided (any grid size correct).
// ---------------------------------------------------------------------------
__global__ __launch_bounds__(256) void mega(AllArgs a) {
  __shared__ alignas(16) char smem[32768];
  cg::grid_group grid = cg::this_grid();
  const int b = blockIdx.x;
  const int G = gridDim.x;

#pragma unroll 1
  for (int u = b; u < 9216; u += G) { prep_unit(a, u, smem); __syncthreads(); }
  grid.sync();

#pragma unroll 1
  for (int t = b; t < 384; t += G) {
    const int z = t >> 6, tt = t & 63;
    gemm128_body<bf16>(smem, a.A1[z], a.B1[z], a.C1[z], tt & 7, tt >> 3);
  }
  grid.sync();

#pragma unroll 1
  for (int t = b; t < 192; t += G) {
    const int z = t >> 6, tt = t & 63;
    gemm128_body<bf16>(smem, a.A2[z], a.B2[z], a.C2[z], tt & 7, tt >> 3);
  }
  grid.sync();

#pragma unroll 1
  for (int t = b; t < 64; t += G)
    gemm128_body<bf16>(smem, a.A3, a.B3, a.C3, t & 7, t >> 3);
  grid.sync();

#pragma unroll 1
  for (int t = b; t < 64; t += G)
    gemm128_body<bf16>(smem, a.A4, a.B4, a.C4, t & 7, t >> 3);
  grid.sync();

#pragma unroll 1
  for (int t = b; t < 512; t += G)
    gemm128_body<float>(smem, a.Af, a.Bf, a.Cf, t & 7, t >> 3);
}

// ---------------------------------------------------------------------------
// Fallback kernels (ordinary launches), used if cooperative launch fails.
// ---------------------------------------------------------------------------
__global__ __launch_bounds__(256) void fb_prep(AllArgs a) {
  __shared__ alignas(16) char smem[32768];
  prep_unit(a, blockIdx.x, smem);
}
__global__ __launch_bounds__(256) void fb_l1(AllArgs a) {
  __shared__ alignas(16) char smem[32768];
  const int t = blockIdx.x, z = t >> 6, tt = t & 63;
  gemm128_body<bf16>(smem, a.A1[z], a.B1[z], a.C1[z], tt & 7, tt >> 3);
}
__global__ __launch_bounds__(256) void fb_l2(AllArgs a) {
  __shared__ alignas(16) char smem[32768];
  const int t = blockIdx.x, z = t >> 6, tt = t & 63;
  gemm128_body<bf16>(smem, a.A2[z], a.B2[z], a.C2[z], tt & 7, tt >> 3);
}
__global__ __launch_bounds__(256) void fb_l3(AllArgs a) {
  __shared__ alignas(16) char smem[32768];
  gemm128_body<bf16>(smem, a.A3, a.B3, a.C3, blockIdx.x & 7, blockIdx.x >> 3);
}
__global__ __launch_bounds__(256) void fb_l4(AllArgs a) {
  __shared__ alignas(16) char smem[32768];
  gemm128_body<bf16>(smem, a.A4, a.B4, a.C4, blockIdx.x & 7, blockIdx.x >> 3);
}
__global__ __launch_bounds__(256) void fb_final(AllArgs a) {
  __shared__ alignas(16) char smem[32768];
  gemm128_body<float>(smem, a.Af, a.Bf, a.Cf, blockIdx.x & 7, blockIdx.x >> 3);
}

// ---------------------------------------------------------------------------
// Host launcher.
// out = x @ (G * W9 * W8 * W8 * W7 * W6 * W5 * W4 * W3 * W2 * W1 * W0)^T
// Tree: P0=G*W9  P1=(W8*W8)^T  P2=W7*W6  P3=(W5*W4)^T  P4=W3*W2  P5=(W1*W0)^T
//       Q0=NT(P0,P1) Q1t=NT(P3,P2) Q2t=NT(P5,P4); R=NT(Q0,Q1t); F=NT(R,Q2t)
//       out = NT(x, F).   NT(A,B)=A*B^T; transposed nodes via (AB)^T=NT(B^T,A).
// Cooperative launch is attempted with a runtime-validated grid size; any
// failure (incl. capture-unsupported) falls back to the proven 6-kernel path.
// Both paths are bit-identical.
// ---------------------------------------------------------------------------
extern "C" void kernel_launch(void* const* d_in, const int* in_sizes, int n_in,
                              void* d_out, int out_size, void* d_ws, size_t ws_size,
                              hipStream_t stream) {
  const float* x    = (const float*)d_in[0];
  const float* Wsrc = (const float*)d_in[1];   // 10 x 1024 x 1024
  const float* Wdec = (const float*)d_in[2];   // 1024 x 256
  const int*   praw = (const int*)d_in[3];
  float* out = (float*)d_out;

  constexpr size_t MAT  = 1024ull * 1024ull;
  constexpr size_t SLOT = 2ull * 1024 * 1024;  // 2 MiB = one bf16 DxD matrix

  char* ws = (char*)d_ws;
  bf16* Wrm[5];
  for (int i = 0; i < 5; i++) Wrm[i] = (bf16*)(ws + (size_t)i * SLOT);
  bf16* Wt[6];
  for (int i = 0; i < 6; i++) Wt[i] = (bf16*)(ws + (size_t)(5 + i) * SLOT);
  bf16* Gbf = (bf16*)(ws + 11 * SLOT);
  bf16* xbf = (bf16*)(ws + 12 * SLOT);
  bf16* P[6];
  for (int i = 0; i < 6; i++) P[i] = (bf16*)(ws + (size_t)(20 + i) * SLOT);
  bf16* Q[3];
  for (int i = 0; i < 3; i++) Q[i] = (bf16*)(ws + (size_t)(26 + i) * SLOT);
  bf16* Rb = (bf16*)(ws + 29 * SLOT);
  bf16* Fb = (bf16*)(ws + 30 * SLOT);          // total ws use: 62 MiB

  AllArgs aa{};
  const int rmIdx[5] = {1, 3, 5, 7, 8};
  for (int i = 0; i < 5; i++) { aa.cvt_src[i] = Wsrc + (size_t)rmIdx[i] * MAT; aa.cvt_dst[i] = Wrm[i]; }
  const int trIdx[6] = {0, 2, 4, 6, 8, 9};
  for (int i = 0; i < 6; i++) { aa.tr_src[i] = Wsrc + (size_t)trIdx[i] * MAT; aa.tr_dst[i] = Wt[i]; }
  aa.Wdec = Wdec; aa.praw = praw; aa.Gbf = Gbf;
  aa.x = x; aa.xbf = xbf;

  const bf16* l1a[6] = {Gbf, Wt[4], Wrm[3], Wt[2], Wrm[1], Wt[0]};
  const bf16* l1b[6] = {Wt[5], Wrm[4], Wt[3], Wrm[2], Wt[1], Wrm[0]};
  for (int i = 0; i < 6; i++) { aa.A1[i] = l1a[i]; aa.B1[i] = l1b[i]; aa.C1[i] = P[i]; }
  const bf16* l2a[3] = {P[0], P[3], P[5]};
  const bf16* l2b[3] = {P[1], P[2], P[4]};
  for (int i = 0; i < 3; i++) { aa.A2[i] = l2a[i]; aa.B2[i] = l2b[i]; aa.C2[i] = Q[i]; }
  aa.A3 = Q[0]; aa.B3 = Q[1]; aa.C3 = Rb;
  aa.A4 = Rb;   aa.B4 = Q[2]; aa.C4 = Fb;
  aa.Af = xbf;  aa.Bf = Fb;   aa.Cf = out;

  // Runtime-validated cooperative grid size (deterministic host query).
  bool coop_done = false;
  int nbPerCU = 0;
  hipError_t qe = hipOccupancyMaxActiveBlocksPerMultiprocessor(&nbPerCU, mega, 256, 0);
  if (qe == hipSuccess && nbPerCU >= 1) {
    int G = nbPerCU * 256;
    if (G > 512) G = 512;
    void* args[] = {(void*)&aa};
    hipError_t le = hipLaunchCooperativeKernel((const void*)mega, dim3(G),
                                               dim3(256), args, 0, stream);
    coop_done = (le == hipSuccess);
  }

  if (!coop_done) {
    fb_prep <<<dim3(9216), 256, 0, stream>>>(aa);
    fb_l1   <<<dim3(384),  256, 0, stream>>>(aa);
    fb_l2   <<<dim3(192),  256, 0, stream>>>(aa);
    fb_l3   <<<dim3(64),   256, 0, stream>>>(aa);
    fb_l4   <<<dim3(64),   256, 0, stream>>>(aa);
    fb_final<<<dim3(512),  256, 0, stream>>>(aa);
  }

  (void)in_sizes; (void)n_in; (void)out_size; (void)ws_size;
}

// Round 7
// 212.365 us; speedup vs baseline: 1.0491x; 1.0491x over previous
//
#include <hip/hip_runtime.h>
#include <stdint.h>
#include <stddef.h>

typedef __bf16 bf16;
typedef __bf16 bf16x8 __attribute__((ext_vector_type(8)));
typedef float f32x4 __attribute__((ext_vector_type(4)));

// ---------------------------------------------------------------------------
// async global->LDS, 16B per lane. LDS dest is wave-uniform base + lane*16.
// ---------------------------------------------------------------------------
__device__ __forceinline__ void global_to_lds16(const void* g, void* l) {
  const __attribute__((address_space(1))) unsigned* gp =
      reinterpret_cast<const __attribute__((address_space(1))) unsigned*>(
          reinterpret_cast<uintptr_t>(g));
  __attribute__((address_space(3))) unsigned* lp =
      reinterpret_cast<__attribute__((address_space(3))) unsigned*>(
          reinterpret_cast<uintptr_t>(l));
  __builtin_amdgcn_global_load_lds(gp, lp, 16, 0, 0);
}

// ---------------------------------------------------------------------------
// XCD-aware tile swizzle for 64-tile (8x8) GEMMs. With round-robin XCD
// dispatch (xcd = blockIdx % 8), the 8 tiles owned by one XCD form a 2x4
// panel rectangle (2 B-panels + 4 A-panels = 1.5 MB) instead of a full
// row/column (which forces each XCD to fetch an entire matrix into its
// private L2). Bijection: bx from bits {t3,t1,t0}, by from bits {t5,t4,t2}.
// ---------------------------------------------------------------------------
__device__ __forceinline__ void tile8x8_swizzle(int t, int& bx, int& by) {
  bx = (((t >> 3) & 1) << 2) | (t & 3);
  by = (((t >> 4) & 3) << 1) | ((t >> 2) & 1);
}

// ---------------------------------------------------------------------------
// 128x128-tile NT GEMM body, BK=64 (8 global_load_lds issues, 32 MFMA,
// one barrier pair per 64 K). C = A * B^T. K=1024, lda=ldb=ldc=1024.
// K-accumulation order identical across rounds -> bit-identical results.
// ---------------------------------------------------------------------------
template <typename OutT>
__device__ __forceinline__ void gemm128_body(const bf16* __restrict__ A,
                                             const bf16* __restrict__ B,
                                             OutT* __restrict__ C,
                                             int bx, int by) {
  __shared__ bf16 As[2][128 * 32];   // [k-half][row*32+col]
  __shared__ bf16 Bs[2][128 * 32];

  const int tid = threadIdx.x;
  const int wave = tid >> 6, lane = tid & 63;
  const int quad = lane >> 4, l16 = lane & 15;
  const int rowBase = by * 128;
  const int colBase = bx * 128;
  const int waveM = (wave >> 1) * 64, waveN = (wave & 1) * 64;

  // staging map: thread t covers global row t/4, cols (t&3)*8 .. +7
  const int sr = tid >> 2;
  const int sc = (tid & 3) * 8;
  const bf16* Ag0 = A + (size_t)(rowBase + sr) * 1024 + sc;   // rows 0..63
  const bf16* Ag1 = Ag0 + (size_t)64 * 1024;                  // rows 64..127
  const bf16* Bg0 = B + (size_t)(colBase + sr) * 1024 + sc;
  const bf16* Bg1 = Bg0 + (size_t)64 * 1024;

  char* lA0  = (char*)As[0] + wave * 1024;  // rows 0..63, k-half 0
  char* lA0b = lA0 + 4096;                  // rows 64..127
  char* lA1  = (char*)As[1] + wave * 1024;  // k-half 1
  char* lA1b = lA1 + 4096;
  char* lB0  = (char*)Bs[0] + wave * 1024;
  char* lB0b = lB0 + 4096;
  char* lB1  = (char*)Bs[1] + wave * 1024;
  char* lB1b = lB1 + 4096;

  f32x4 acc[4][4] = {};

  for (int k0 = 0; k0 < 1024; k0 += 64) {
    global_to_lds16(Ag0 + k0,      lA0);
    global_to_lds16(Ag1 + k0,      lA0b);
    global_to_lds16(Ag0 + k0 + 32, lA1);
    global_to_lds16(Ag1 + k0 + 32, lA1b);
    global_to_lds16(Bg0 + k0,      lB0);
    global_to_lds16(Bg1 + k0,      lB0b);
    global_to_lds16(Bg0 + k0 + 32, lB1);
    global_to_lds16(Bg1 + k0 + 32, lB1b);
    __syncthreads();
#pragma unroll
    for (int kk = 0; kk < 2; kk++) {
      bf16x8 af[4], bfr[4];
#pragma unroll
      for (int mi = 0; mi < 4; mi++)
        af[mi] = *(const bf16x8*)(As[kk] + (waveM + mi * 16 + l16) * 32 + quad * 8);
#pragma unroll
      for (int ni = 0; ni < 4; ni++)
        bfr[ni] = *(const bf16x8*)(Bs[kk] + (waveN + ni * 16 + l16) * 32 + quad * 8);
#pragma unroll
      for (int mi = 0; mi < 4; mi++)
#pragma unroll
        for (int ni = 0; ni < 4; ni++)
          acc[mi][ni] = __builtin_amdgcn_mfma_f32_16x16x32_bf16(af[mi], bfr[ni],
                                                                acc[mi][ni], 0, 0, 0);
    }
    __syncthreads();
  }

  OutT* Cb = C + (size_t)(rowBase + waveM) * 1024 + colBase + waveN;
#pragma unroll
  for (int mi = 0; mi < 4; mi++)
#pragma unroll
    for (int ni = 0; ni < 4; ni++)
#pragma unroll
      for (int r = 0; r < 4; r++)
        Cb[(size_t)(mi * 16 + quad * 4 + r) * 1024 + ni * 16 + l16] =
            (OutT)acc[mi][ni][r];
}

// ---------------------------------------------------------------------------
// fused prep kernel. Flat grid of 5120 independent blocks:
//   [0,    2560)  : fp32->bf16 convert of 5 row-major Ws (512 blocks each)
//   [2560, 4096)  : fp32->bf16 transpose of 6 Ws (256 blocks each)
//   [4096, 5120)  : G build, one block per row j (LDS scatter via perm)
// ---------------------------------------------------------------------------
struct PrepArgs {
  const float* cvt_src[5]; bf16* cvt_dst[5];
  const float* tr_src[6];  bf16* tr_dst[6];
  const float* Wdec; const int* praw; bf16* Gbf;
};

__global__ __launch_bounds__(256) void prep_all(PrepArgs p) {
  __shared__ alignas(16) char smem[64 * 65 * 2];
  const int b = blockIdx.x;
  const int tid = threadIdx.x;

  if (b < 2560) {  // ---- convert row-major W ----
    const int m = b >> 9, blk = b & 511;
    const float* __restrict__ src = p.cvt_src[m];
    bf16* __restrict__ dst = p.cvt_dst[m];
    const int i = (blk * 256 + tid) * 8;
    float4 a = *(const float4*)(src + i);
    float4 c = *(const float4*)(src + i + 4);
    bf16x8 o;
    o[0] = (bf16)a.x; o[1] = (bf16)a.y; o[2] = (bf16)a.z; o[3] = (bf16)a.w;
    o[4] = (bf16)c.x; o[5] = (bf16)c.y; o[6] = (bf16)c.z; o[7] = (bf16)c.w;
    *(bf16x8*)(dst + i) = o;
  } else if (b < 4096) {  // ---- transpose+convert W ----
    const int t = b - 2560;
    const int m = t >> 8, r = t & 255;
    const float* __restrict__ src = p.tr_src[m];
    bf16* __restrict__ dst = p.tr_dst[m];
    bf16(*tile)[65] = reinterpret_cast<bf16(*)[65]>(smem);
    const int bx = (r & 15) * 64;
    const int by = (r >> 4) * 64;
    const int tx = tid & 63;
    const int ty4 = tid >> 6;
#pragma unroll
    for (int rr = 0; rr < 16; rr++) {
      int row = ty4 * 16 + rr;
      tile[row][tx] = (bf16)src[(size_t)(by + row) * 1024 + bx + tx];
    }
    __syncthreads();
#pragma unroll
    for (int rr = 0; rr < 16; rr++) {
      int row = ty4 * 16 + rr;
      dst[(size_t)(bx + row) * 1024 + by + tx] = tile[tx][row];
    }
  } else {  // ---- G build: G[j,d] = sum_{k: perm[k]==d} W_dec[j,k] ----
    const int j = b - 4096;
    float* row = (float*)smem;
    int* perm_l = (int*)(smem + 4096);
    int* nzp = (int*)(smem + 4096 + 1024);
#pragma unroll
    for (int c = 0; c < 4; c++) row[tid * 4 + c] = 0.f;
    if (tid == 0) *nzp = 0;
    __syncthreads();
    // int64 little-endian perm has all-zero high words.
    if (tid < 128 && p.praw[2 * tid + 1] != 0) atomicOr(nzp, 1);
    __syncthreads();
    const int is64 = (*nzp == 0);
    perm_l[tid] = is64 ? p.praw[2 * tid] : p.praw[tid];
    __syncthreads();
    atomicAdd(&row[perm_l[tid]], p.Wdec[(size_t)j * 256 + tid]);
    __syncthreads();
#pragma unroll
    for (int c = 0; c < 4; c++)
      p.Gbf[(size_t)j * 1024 + tid * 4 + c] = (bf16)row[tid * 4 + c];
  }
}

// ---------------------------------------------------------------------------
// Tree-level kernel: blocks [0, nG*64) do batched 128-tile NT GEMMs with
// XCD-aware tile swizzle; blocks >= nG*64 do x fp32->bf16 convert filler.
// ---------------------------------------------------------------------------
struct TreeArgs {
  const bf16* A[6]; const bf16* B[6]; bf16* C[6];
  int nG;
  const float* x; bf16* xbf; int ubase;
};

__global__ __launch_bounds__(256) void tree_level(TreeArgs a) {
  const int b = blockIdx.x;
  const int gBlocks = a.nG * 64;
  if (b < gBlocks) {
    const int z = b >> 6, t = b & 63;
    int bx, by;
    tile8x8_swizzle(t, bx, by);
    gemm128_body<bf16>(a.A[z], a.B[z], a.C[z], bx, by);
  } else {
    const int unit = a.ubase + (b - gBlocks);
    const int i = unit * 2048 + (int)threadIdx.x * 8;
    float4 v0 = *(const float4*)(a.x + i);
    float4 v1 = *(const float4*)(a.x + i + 4);
    bf16x8 o;
    o[0] = (bf16)v0.x; o[1] = (bf16)v0.y; o[2] = (bf16)v0.z; o[3] = (bf16)v0.w;
    o[4] = (bf16)v1.x; o[5] = (bf16)v1.y; o[6] = (bf16)v1.z; o[7] = (bf16)v1.w;
    *(bf16x8*)(a.xbf + i) = o;
  }
}

// ---------------------------------------------------------------------------
// Final: out = x * F^T, fp32 out. M=8192, N=1024, K=1024. Flat 512-block
// grid with bx = b>>6, by = b&63: XCD k (b%8==k) owns by ≡ k (mod 8), i.e.
// 8 A-panels (2 MB) + all 8 B-panels (2 MB) = 4 MB working set (fits its
// private L2), instead of the whole 16.8 MB A matrix per XCD.
// ---------------------------------------------------------------------------
__global__ __launch_bounds__(256) void final_gemm(const bf16* __restrict__ A,
                                                  const bf16* __restrict__ B,
                                                  float* __restrict__ C) {
  const int b = blockIdx.x;
  gemm128_body<float>(A, B, C, b >> 6, b & 63);
}

// ---------------------------------------------------------------------------
// Host launcher.  6 kernels.
// out = x @ (G * W9 * W8 * W8 * W7 * W6 * W5 * W4 * W3 * W2 * W1 * W0)^T
// Tree: P0=G*W9  P1=(W8*W8)^T  P2=W7*W6  P3=(W5*W4)^T  P4=W3*W2  P5=(W1*W0)^T
//       Q0=NT(P0,P1) Q1t=NT(P3,P2) Q2t=NT(P5,P4); R=NT(Q0,Q1t); F=NT(R,Q2t)
//       out = NT(x, F).   NT(A,B)=A*B^T; transposed nodes via (AB)^T=NT(B^T,A).
// x convert spread across L2/L3/L4 as filler (only needed by final GEMM).
// ---------------------------------------------------------------------------
extern "C" void kernel_launch(void* const* d_in, const int* in_sizes, int n_in,
                              void* d_out, int out_size, void* d_ws, size_t ws_size,
                              hipStream_t stream) {
  const float* x    = (const float*)d_in[0];
  const float* Wsrc = (const float*)d_in[1];   // 10 x 1024 x 1024
  const float* Wdec = (const float*)d_in[2];   // 1024 x 256
  const int*   praw = (const int*)d_in[3];
  float* out = (float*)d_out;

  constexpr size_t MAT  = 1024ull * 1024ull;
  constexpr size_t SLOT = 2ull * 1024 * 1024;  // 2 MiB = one bf16 DxD matrix

  char* ws = (char*)d_ws;
  bf16* Wrm[5];  // W1, W3, W5, W7, W8 (row-major bf16)
  for (int i = 0; i < 5; i++) Wrm[i] = (bf16*)(ws + (size_t)i * SLOT);
  bf16* Wt[6];   // W0^T, W2^T, W4^T, W6^T, W8^T, W9^T
  for (int i = 0; i < 6; i++) Wt[i] = (bf16*)(ws + (size_t)(5 + i) * SLOT);
  bf16* Gbf = (bf16*)(ws + 11 * SLOT);
  bf16* xbf = (bf16*)(ws + 12 * SLOT);         // 8 slots (16 MiB)
  bf16* P[6];
  for (int i = 0; i < 6; i++) P[i] = (bf16*)(ws + (size_t)(20 + i) * SLOT);
  bf16* Q[3];
  for (int i = 0; i < 3; i++) Q[i] = (bf16*)(ws + (size_t)(26 + i) * SLOT);
  bf16* Rb = (bf16*)(ws + 29 * SLOT);
  bf16* Fb = (bf16*)(ws + 30 * SLOT);          // total ws use: 62 MiB

  // 1) fused prep (W converts, W transposes, G)
  PrepArgs pa;
  const int rmIdx[5] = {1, 3, 5, 7, 8};
  for (int i = 0; i < 5; i++) { pa.cvt_src[i] = Wsrc + (size_t)rmIdx[i] * MAT; pa.cvt_dst[i] = Wrm[i]; }
  const int trIdx[6] = {0, 2, 4, 6, 8, 9};
  for (int i = 0; i < 6; i++) { pa.tr_src[i] = Wsrc + (size_t)trIdx[i] * MAT; pa.tr_dst[i] = Wt[i]; }
  pa.Wdec = Wdec; pa.praw = praw; pa.Gbf = Gbf;
  prep_all<<<dim3(5120), 256, 0, stream>>>(pa);

  // 2) L1: 6 GEMMs only (384 blocks; completion gates L2 -> keep it lean)
  TreeArgs L1{};
  const bf16* l1a[6] = {Gbf, Wt[4], Wrm[3], Wt[2], Wrm[1], Wt[0]};
  const bf16* l1b[6] = {Wt[5], Wrm[4], Wt[3], Wrm[2], Wt[1], Wrm[0]};
  for (int i = 0; i < 6; i++) { L1.A[i] = l1a[i]; L1.B[i] = l1b[i]; L1.C[i] = P[i]; }
  L1.nG = 6; L1.x = x; L1.xbf = xbf; L1.ubase = 0;
  tree_level<<<dim3(384), 256, 0, stream>>>(L1);

  // 3) L2: Q0=NT(P0,P1) Q1t=NT(P3,P2) Q2t=NT(P5,P4)  + xcvt units [0,1360)
  TreeArgs L2{};
  const bf16* l2a[3] = {P[0], P[3], P[5]};
  const bf16* l2b[3] = {P[1], P[2], P[4]};
  for (int i = 0; i < 3; i++) { L2.A[i] = l2a[i]; L2.B[i] = l2b[i]; L2.C[i] = Q[i]; }
  L2.nG = 3; L2.x = x; L2.xbf = xbf; L2.ubase = 0;
  tree_level<<<dim3(192 + 1360), 256, 0, stream>>>(L2);

  // 4) L3: R = NT(Q0, Q1t)  + xcvt units [1360,2720)
  TreeArgs L3{};
  L3.A[0] = Q[0]; L3.B[0] = Q[1]; L3.C[0] = Rb;
  L3.nG = 1; L3.x = x; L3.xbf = xbf; L3.ubase = 1360;
  tree_level<<<dim3(64 + 1360), 256, 0, stream>>>(L3);

  // 5) L4: F = NT(R, Q2t)  + xcvt units [2720,4096)
  TreeArgs L4{};
  L4.A[0] = Rb; L4.B[0] = Q[2]; L4.C[0] = Fb;
  L4.nG = 1; L4.x = x; L4.xbf = xbf; L4.ubase = 2720;
  tree_level<<<dim3(64 + 1376), 256, 0, stream>>>(L4);

  // 6) out = NT(x, F), fp32 out (XCD-swizzled flat grid)
  final_gemm<<<dim3(512), 256, 0, stream>>>(xbf, Fb, out);

  (void)in_sizes; (void)n_in; (void)out_size; (void)ws_size;
}

// Round 8
// 197.174 us; speedup vs baseline: 1.1299x; 1.0770x over previous
//
#include <hip/hip_runtime.h>
#include <stdint.h>
#include <stddef.h>

typedef __bf16 bf16;
typedef __bf16 bf16x8 __attribute__((ext_vector_type(8)));
typedef float f32x4 __attribute__((ext_vector_type(4)));

// ---------------------------------------------------------------------------
// async global->LDS, 16B per lane. LDS dest is wave-uniform base + lane*16.
// ---------------------------------------------------------------------------
__device__ __forceinline__ void global_to_lds16(const void* g, void* l) {
  const __attribute__((address_space(1))) unsigned* gp =
      reinterpret_cast<const __attribute__((address_space(1))) unsigned*>(
          reinterpret_cast<uintptr_t>(g));
  __attribute__((address_space(3))) unsigned* lp =
      reinterpret_cast<__attribute__((address_space(3))) unsigned*>(
          reinterpret_cast<uintptr_t>(l));
  __builtin_amdgcn_global_load_lds(gp, lp, 16, 0, 0);
}

// ---------------------------------------------------------------------------
// XCD-aware tile swizzle for 64-tile (8x8) GEMMs (see R7 comment).
// ---------------------------------------------------------------------------
__device__ __forceinline__ void tile8x8_swizzle(int t, int& bx, int& by) {
  bx = (((t >> 3) & 1) << 2) | (t & 3);
  by = (((t >> 4) & 3) << 1) | ((t >> 2) & 1);
}

// ---------------------------------------------------------------------------
// 128x128-tile NT GEMM body, BK=64, PING-PONG double-buffered LDS (64 KB).
// One barrier per K-iteration:
//   issue tile0->buf0;  loop: { barrier; issue k+1 -> buf[p^1]; compute buf[p] }
// The compiler's vmcnt(0)-at-barrier then drains loads issued a full compute
// phase earlier -> exposed load latency per iter drops by the MFMA time.
// This targets the latency-bound tree stages (0.25-1.5 blocks/CU).
// C = A * B^T. K=1024, lda=ldb=ldc=1024. K-order unchanged -> bit-identical.
// ---------------------------------------------------------------------------
template <typename OutT>
__device__ __forceinline__ void gemm128_body(const bf16* __restrict__ A,
                                             const bf16* __restrict__ B,
                                             OutT* __restrict__ C,
                                             int bx, int by) {
  __shared__ bf16 As[2][128 * 64];   // [buf][half*4096 + row*32 + col]
  __shared__ bf16 Bs[2][128 * 64];

  const int tid = threadIdx.x;
  const int wave = tid >> 6, lane = tid & 63;
  const int quad = lane >> 4, l16 = lane & 15;
  const int rowBase = by * 128;
  const int colBase = bx * 128;
  const int waveM = (wave >> 1) * 64, waveN = (wave & 1) * 64;

  // staging map: thread t covers global row t/4, cols (t&3)*8 .. +7
  const int sr = tid >> 2;
  const int sc = (tid & 3) * 8;
  const bf16* Ag0 = A + (size_t)(rowBase + sr) * 1024 + sc;   // rows 0..63
  const bf16* Ag1 = Ag0 + (size_t)64 * 1024;                  // rows 64..127
  const bf16* Bg0 = B + (size_t)(colBase + sr) * 1024 + sc;
  const bf16* Bg1 = Bg0 + (size_t)64 * 1024;

  const int woff = wave * 1024;  // byte offset of this wave's 16-row slab

  // issue the 8 async 16B/lane loads for K-tile starting at k0 into buffer p
  auto issue = [&](int k0, int p) {
    char* aB = (char*)As[p] + woff;
    char* bB = (char*)Bs[p] + woff;
    global_to_lds16(Ag0 + k0,      aB);             // half0 rows 0..63
    global_to_lds16(Ag1 + k0,      aB + 4096);      // half0 rows 64..127
    global_to_lds16(Ag0 + k0 + 32, aB + 8192);      // half1 rows 0..63
    global_to_lds16(Ag1 + k0 + 32, aB + 12288);     // half1 rows 64..127
    global_to_lds16(Bg0 + k0,      bB);
    global_to_lds16(Bg1 + k0,      bB + 4096);
    global_to_lds16(Bg0 + k0 + 32, bB + 8192);
    global_to_lds16(Bg1 + k0 + 32, bB + 12288);
  };

  f32x4 acc[4][4] = {};

  issue(0, 0);
  int p = 0;
#pragma unroll 1
  for (int k0 = 0; k0 < 1024; k0 += 64, p ^= 1) {
    __syncthreads();                 // drains loads for tile k0 (buf p)
    if (k0 + 64 < 1024) issue(k0 + 64, p ^ 1);   // prefetch into other buf
#pragma unroll
    for (int kk = 0; kk < 2; kk++) {
      const bf16* base = As[p] + kk * 4096;
      const bf16* baseB = Bs[p] + kk * 4096;
      bf16x8 af[4], bfr[4];
#pragma unroll
      for (int mi = 0; mi < 4; mi++)
        af[mi] = *(const bf16x8*)(base + (waveM + mi * 16 + l16) * 32 + quad * 8);
#pragma unroll
      for (int ni = 0; ni < 4; ni++)
        bfr[ni] = *(const bf16x8*)(baseB + (waveN + ni * 16 + l16) * 32 + quad * 8);
#pragma unroll
      for (int mi = 0; mi < 4; mi++)
#pragma unroll
        for (int ni = 0; ni < 4; ni++)
          acc[mi][ni] = __builtin_amdgcn_mfma_f32_16x16x32_bf16(af[mi], bfr[ni],
                                                                acc[mi][ni], 0, 0, 0);
    }
  }

  OutT* Cb = C + (size_t)(rowBase + waveM) * 1024 + colBase + waveN;
#pragma unroll
  for (int mi = 0; mi < 4; mi++)
#pragma unroll
    for (int ni = 0; ni < 4; ni++)
#pragma unroll
      for (int r = 0; r < 4; r++)
        Cb[(size_t)(mi * 16 + quad * 4 + r) * 1024 + ni * 16 + l16] =
            (OutT)acc[mi][ni][r];
}

// ---------------------------------------------------------------------------
// fused prep kernel. Flat grid of 5120 independent blocks:
//   [0,    2560)  : fp32->bf16 convert of 5 row-major Ws (512 blocks each)
//   [2560, 4096)  : fp32->bf16 transpose of 6 Ws (256 blocks each)
//   [4096, 5120)  : G build, one block per row j (LDS scatter via perm)
// ---------------------------------------------------------------------------
struct PrepArgs {
  const float* cvt_src[5]; bf16* cvt_dst[5];
  const float* tr_src[6];  bf16* tr_dst[6];
  const float* Wdec; const int* praw; bf16* Gbf;
};

__global__ __launch_bounds__(256) void prep_all(PrepArgs p) {
  __shared__ alignas(16) char smem[64 * 65 * 2];
  const int b = blockIdx.x;
  const int tid = threadIdx.x;

  if (b < 2560) {  // ---- convert row-major W ----
    const int m = b >> 9, blk = b & 511;
    const float* __restrict__ src = p.cvt_src[m];
    bf16* __restrict__ dst = p.cvt_dst[m];
    const int i = (blk * 256 + tid) * 8;
    float4 a = *(const float4*)(src + i);
    float4 c = *(const float4*)(src + i + 4);
    bf16x8 o;
    o[0] = (bf16)a.x; o[1] = (bf16)a.y; o[2] = (bf16)a.z; o[3] = (bf16)a.w;
    o[4] = (bf16)c.x; o[5] = (bf16)c.y; o[6] = (bf16)c.z; o[7] = (bf16)c.w;
    *(bf16x8*)(dst + i) = o;
  } else if (b < 4096) {  // ---- transpose+convert W ----
    const int t = b - 2560;
    const int m = t >> 8, r = t & 255;
    const float* __restrict__ src = p.tr_src[m];
    bf16* __restrict__ dst = p.tr_dst[m];
    bf16(*tile)[65] = reinterpret_cast<bf16(*)[65]>(smem);
    const int bx = (r & 15) * 64;
    const int by = (r >> 4) * 64;
    const int tx = tid & 63;
    const int ty4 = tid >> 6;
#pragma unroll
    for (int rr = 0; rr < 16; rr++) {
      int row = ty4 * 16 + rr;
      tile[row][tx] = (bf16)src[(size_t)(by + row) * 1024 + bx + tx];
    }
    __syncthreads();
#pragma unroll
    for (int rr = 0; rr < 16; rr++) {
      int row = ty4 * 16 + rr;
      dst[(size_t)(bx + row) * 1024 + by + tx] = tile[tx][row];
    }
  } else {  // ---- G build: G[j,d] = sum_{k: perm[k]==d} W_dec[j,k] ----
    const int j = b - 4096;
    float* row = (float*)smem;
    int* perm_l = (int*)(smem + 4096);
    int* nzp = (int*)(smem + 4096 + 1024);
#pragma unroll
    for (int c = 0; c < 4; c++) row[tid * 4 + c] = 0.f;
    if (tid == 0) *nzp = 0;
    __syncthreads();
    // int64 little-endian perm has all-zero high words.
    if (tid < 128 && p.praw[2 * tid + 1] != 0) atomicOr(nzp, 1);
    __syncthreads();
    const int is64 = (*nzp == 0);
    perm_l[tid] = is64 ? p.praw[2 * tid] : p.praw[tid];
    __syncthreads();
    atomicAdd(&row[perm_l[tid]], p.Wdec[(size_t)j * 256 + tid]);
    __syncthreads();
#pragma unroll
    for (int c = 0; c < 4; c++)
      p.Gbf[(size_t)j * 1024 + tid * 4 + c] = (bf16)row[tid * 4 + c];
  }
}

// ---------------------------------------------------------------------------
// Tree-level kernel: blocks [0, nG*64) do batched 128-tile NT GEMMs with
// XCD-aware tile swizzle; blocks >= nG*64 do x fp32->bf16 convert filler.
// ---------------------------------------------------------------------------
struct TreeArgs {
  const bf16* A[6]; const bf16* B[6]; bf16* C[6];
  int nG;
  const float* x; bf16* xbf; int ubase;
};

__global__ __launch_bounds__(256) void tree_level(TreeArgs a) {
  const int b = blockIdx.x;
  const int gBlocks = a.nG * 64;
  if (b < gBlocks) {
    const int z = b >> 6, t = b & 63;
    int bx, by;
    tile8x8_swizzle(t, bx, by);
    gemm128_body<bf16>(a.A[z], a.B[z], a.C[z], bx, by);
  } else {
    const int unit = a.ubase + (b - gBlocks);
    const int i = unit * 2048 + (int)threadIdx.x * 8;
    float4 v0 = *(const float4*)(a.x + i);
    float4 v1 = *(const float4*)(a.x + i + 4);
    bf16x8 o;
    o[0] = (bf16)v0.x; o[1] = (bf16)v0.y; o[2] = (bf16)v0.z; o[3] = (bf16)v0.w;
    o[4] = (bf16)v1.x; o[5] = (bf16)v1.y; o[6] = (bf16)v1.z; o[7] = (bf16)v1.w;
    *(bf16x8*)(a.xbf + i) = o;
  }
}

// ---------------------------------------------------------------------------
// Final: out = x * F^T, fp32 out. M=8192, N=1024, K=1024. Flat 512-block
// grid with bx = b>>6, by = b&63: XCD k (b%8==k) owns 8 A-panels + 8
// B-panels = 4 MB working set (fits its private L2).
// ---------------------------------------------------------------------------
__global__ __launch_bounds__(256) void final_gemm(const bf16* __restrict__ A,
                                                  const bf16* __restrict__ B,
                                                  float* __restrict__ C) {
  const int b = blockIdx.x;
  gemm128_body<float>(A, B, C, b >> 6, b & 63);
}

// ---------------------------------------------------------------------------
// Host launcher.  6 kernels.
// out = x @ (G * W9 * W8 * W8 * W7 * W6 * W5 * W4 * W3 * W2 * W1 * W0)^T
// Tree: P0=G*W9  P1=(W8*W8)^T  P2=W7*W6  P3=(W5*W4)^T  P4=W3*W2  P5=(W1*W0)^T
//       Q0=NT(P0,P1) Q1t=NT(P3,P2) Q2t=NT(P5,P4); R=NT(Q0,Q1t); F=NT(R,Q2t)
//       out = NT(x, F).   NT(A,B)=A*B^T; transposed nodes via (AB)^T=NT(B^T,A).
// x convert spread across L2/L3/L4 as filler (only needed by final GEMM).
// ---------------------------------------------------------------------------
extern "C" void kernel_launch(void* const* d_in, const int* in_sizes, int n_in,
                              void* d_out, int out_size, void* d_ws, size_t ws_size,
                              hipStream_t stream) {
  const float* x    = (const float*)d_in[0];
  const float* Wsrc = (const float*)d_in[1];   // 10 x 1024 x 1024
  const float* Wdec = (const float*)d_in[2];   // 1024 x 256
  const int*   praw = (const int*)d_in[3];
  float* out = (float*)d_out;

  constexpr size_t MAT  = 1024ull * 1024ull;
  constexpr size_t SLOT = 2ull * 1024 * 1024;  // 2 MiB = one bf16 DxD matrix

  char* ws = (char*)d_ws;
  bf16* Wrm[5];  // W1, W3, W5, W7, W8 (row-major bf16)
  for (int i = 0; i < 5; i++) Wrm[i] = (bf16*)(ws + (size_t)i * SLOT);
  bf16* Wt[6];   // W0^T, W2^T, W4^T, W6^T, W8^T, W9^T
  for (int i = 0; i < 6; i++) Wt[i] = (bf16*)(ws + (size_t)(5 + i) * SLOT);
  bf16* Gbf = (bf16*)(ws + 11 * SLOT);
  bf16* xbf = (bf16*)(ws + 12 * SLOT);         // 8 slots (16 MiB)
  bf16* P[6];
  for (int i = 0; i < 6; i++) P[i] = (bf16*)(ws + (size_t)(20 + i) * SLOT);
  bf16* Q[3];
  for (int i = 0; i < 3; i++) Q[i] = (bf16*)(ws + (size_t)(26 + i) * SLOT);
  bf16* Rb = (bf16*)(ws + 29 * SLOT);
  bf16* Fb = (bf16*)(ws + 30 * SLOT);          // total ws use: 62 MiB

  // 1) fused prep (W converts, W transposes, G)
  PrepArgs pa;
  const int rmIdx[5] = {1, 3, 5, 7, 8};
  for (int i = 0; i < 5; i++) { pa.cvt_src[i] = Wsrc + (size_t)rmIdx[i] * MAT; pa.cvt_dst[i] = Wrm[i]; }
  const int trIdx[6] = {0, 2, 4, 6, 8, 9};
  for (int i = 0; i < 6; i++) { pa.tr_src[i] = Wsrc + (size_t)trIdx[i] * MAT; pa.tr_dst[i] = Wt[i]; }
  pa.Wdec = Wdec; pa.praw = praw; pa.Gbf = Gbf;
  prep_all<<<dim3(5120), 256, 0, stream>>>(pa);

  // 2) L1: 6 GEMMs only (384 blocks; completion gates L2 -> keep it lean)
  TreeArgs L1{};
  const bf16* l1a[6] = {Gbf, Wt[4], Wrm[3], Wt[2], Wrm[1], Wt[0]};
  const bf16* l1b[6] = {Wt[5], Wrm[4], Wt[3], Wrm[2], Wt[1], Wrm[0]};
  for (int i = 0; i < 6; i++) { L1.A[i] = l1a[i]; L1.B[i] = l1b[i]; L1.C[i] = P[i]; }
  L1.nG = 6; L1.x = x; L1.xbf = xbf; L1.ubase = 0;
  tree_level<<<dim3(384), 256, 0, stream>>>(L1);

  // 3) L2: Q0=NT(P0,P1) Q1t=NT(P3,P2) Q2t=NT(P5,P4)  + xcvt units [0,1360)
  TreeArgs L2{};
  const bf16* l2a[3] = {P[0], P[3], P[5]};
  const bf16* l2b[3] = {P[1], P[2], P[4]};
  for (int i = 0; i < 3; i++) { L2.A[i] = l2a[i]; L2.B[i] = l2b[i]; L2.C[i] = Q[i]; }
  L2.nG = 3; L2.x = x; L2.xbf = xbf; L2.ubase = 0;
  tree_level<<<dim3(192 + 1360), 256, 0, stream>>>(L2);

  // 4) L3: R = NT(Q0, Q1t)  + xcvt units [1360,2720)
  TreeArgs L3{};
  L3.A[0] = Q[0]; L3.B[0] = Q[1]; L3.C[0] = Rb;
  L3.nG = 1; L3.x = x; L3.xbf = xbf; L3.ubase = 1360;
  tree_level<<<dim3(64 + 1360), 256, 0, stream>>>(L3);

  // 5) L4: F = NT(R, Q2t)  + xcvt units [2720,4096)
  TreeArgs L4{};
  L4.A[0] = Rb; L4.B[0] = Q[2]; L4.C[0] = Fb;
  L4.nG = 1; L4.x = x; L4.xbf = xbf; L4.ubase = 2720;
  tree_level<<<dim3(64 + 1376), 256, 0, stream>>>(L4);

  // 6) out = NT(x, F), fp32 out (XCD-swizzled flat grid)
  final_gemm<<<dim3(512), 256, 0, stream>>>(xbf, Fb, out);

  (void)in_sizes; (void)n_in; (void)out_size; (void)ws_size;
}